// Round 15
// baseline (2633.684 us; speedup 1.0000x reference)
//
#include <hip/hip_runtime.h>
#include <math.h>

#define VSZ 32000
#define EDIM 128
#define HDIM 256
#define BSZ 256
#define SLEN 256
#define ANUM 8
#define SALEN 32
#define G3 768
#define TB 16            // sequences per block (one M-tile)
#define PADW 392         // xh row length in shorts (384 + 8 pad)

// WB: split-bf16 weight fragments: [enc4][kk12][wv8][slot6][hi/lo 2][512 shorts]
// slot = c2*3 + gate. Recurrence uses hi-only weights; A-side (x,h) split hi+lo.
// Residency (8-wave block): kk2,3,4,7,8 in AGPRs (30 frags = 120 AGPR, via
// inline-asm "a"-constraint MFMA - the allocator refuses arch-VGPR residency,
// r11-r13), kk5,6 in LDS (96KB), kk0,1,9,10,11 streamed from L2 (240 KB/step).
#define WB_SHORTS (4 * 12 * 8 * 6 * 2 * 512)    // 2,359,296 shorts = 4.72 MB
#define KK_STRIDE (8 * 6 * 2 * 512)             // 49152 shorts per kk
#define WV_STRIDE (6 * 2 * 512)                 // 6144 shorts per wv
#define OFF_HWT   (WB_SHORTS / 2)               // float offset
#define HWT_SIZE  (1024 * HDIM)
#define OFF_STATE (OFF_HWT + HWT_SIZE)
#define OFF_ACT   (OFF_STATE + BSZ * G3)

typedef __attribute__((ext_vector_type(8))) short bf16x8;
typedef __attribute__((ext_vector_type(4))) short bf16x4;
typedef __attribute__((ext_vector_type(4))) float f32x4;

__device__ __forceinline__ unsigned short bf16_rne(float f) {
    unsigned int u = __builtin_bit_cast(unsigned int, f);
    unsigned int r = (u + 0x7FFFu + ((u >> 16) & 1u)) >> 16;
    return (unsigned short)r;
}
__device__ __forceinline__ float bf16_to_f32(unsigned short h) {
    unsigned int u = ((unsigned int)h) << 16;
    return __builtin_bit_cast(float, u);
}

// B-fragment: lane l elem q -> B[k = 32*kk + 8*(l>>4) + q][n], n = 256*g3 + 16*(wv+8*cc2) + (l&15)
__global__ void prep_frag(const float* __restrict__ Wih, const float* __restrict__ Whh,
                          unsigned short* __restrict__ WB) {
    int idx = blockIdx.x * 256 + threadIdx.x;      // < 1,179,648 (hi elements)
    int q = idx & 7;
    int l = (idx >> 3) & 63;
    int rest = idx >> 9;
    int slot = rest % 6; rest /= 6;                // slot = cc2*3 + g3
    int wv = rest & 7;   rest >>= 3;
    int kk = rest % 12;
    int enc = rest / 12;
    int cc2 = slot / 3, g3 = slot % 3;
    int row = 256 * g3 + 16 * (wv + 8 * cc2) + (l & 15);
    int kloc = 8 * (l >> 4) + q;
    float v;
    if (kk < 4) v = Wih[(enc * G3 + row) * EDIM + 32 * kk + kloc];
    else        v = Whh[(enc * G3 + row) * HDIM + 32 * (kk - 4) + kloc];
    unsigned short hi = bf16_rne(v);
    unsigned short lo = bf16_rne(v - bf16_to_f32(hi));
    size_t base = ((((size_t)(enc * 12 + kk) * 8 + wv) * 6 + slot) * 2) * 512 + l * 8 + q;
    WB[base] = hi;
    WB[base + 512] = lo;
}

__global__ void prep_hwt(const float* __restrict__ hW, float* __restrict__ hWT) {
    int idx = blockIdx.x * 256 + threadIdx.x;
    if (idx >= HWT_SIZE) return;
    int k = idx >> 8;
    int j = idx & 255;
    hWT[idx] = hW[j * 1024 + k];
}

#define MF(A, B, C) __builtin_amdgcn_mfma_f32_16x16x32_bf16(A, B, C, 0, 0, 0)

// MFMA with B operand held in AGPRs (inline asm forces "a" allocation).
// srcC of every use is MFMA-written (HW-forwarded, no hazard nops needed).
__device__ __forceinline__ void mfma_a(f32x4& c, bf16x8 a, bf16x8 b) {
    asm volatile("v_mfma_f32_16x16x32_bf16 %0, %1, %2, %0"
                 : "+v"(c) : "v"(a), "a"(b));
}

// declare the 6 AGPR-resident fragments of kk K (both c2 groups, 3 gates)
#define DECLA(K)                                                                   \
    bf16x8 G##K##R0 = *(const bf16x8*)(WBw + (size_t)(K) * KK_STRIDE);             \
    bf16x8 G##K##Z0 = *(const bf16x8*)(WBw + (size_t)(K) * KK_STRIDE + 1024);      \
    bf16x8 G##K##N0 = *(const bf16x8*)(WBw + (size_t)(K) * KK_STRIDE + 2048);      \
    bf16x8 G##K##R1 = *(const bf16x8*)(WBw + (size_t)(K) * KK_STRIDE + 3072);      \
    bf16x8 G##K##Z1 = *(const bf16x8*)(WBw + (size_t)(K) * KK_STRIDE + 4096);      \
    bf16x8 G##K##N1 = *(const bf16x8*)(WBw + (size_t)(K) * KK_STRIDE + 5120);

// one AGPR-resident kk step (asm MFMA); ACCN = aNX or aNH
#define AGPRK(K, OFF, ACCN) {                                                      \
    bf16x8 Ahi_ = *(const bf16x8*)(&xh_hi[lr][(OFF) + 8 * lg]);                    \
    bf16x8 Alo_ = *(const bf16x8*)(&xh_lo[lr][(OFF) + 8 * lg]);                    \
    mfma_a(aR[0], Ahi_, G##K##R0);   mfma_a(aR[0], Alo_, G##K##R0);                \
    mfma_a(aZ[0], Ahi_, G##K##Z0);   mfma_a(aZ[0], Alo_, G##K##Z0);                \
    mfma_a(ACCN[0], Ahi_, G##K##N0); mfma_a(ACCN[0], Alo_, G##K##N0);              \
    mfma_a(aR[1], Ahi_, G##K##R1);   mfma_a(aR[1], Alo_, G##K##R1);                \
    mfma_a(aZ[1], Ahi_, G##K##Z1);   mfma_a(aZ[1], Alo_, G##K##Z1);                \
    mfma_a(ACCN[1], Ahi_, G##K##N1); mfma_a(ACCN[1], Alo_, G##K##N1); }

// one streamed kk step (intrinsic MFMA); ACCN = aNX or aNH
#define STREAMK(K, OFF, ACCN) {                                                    \
    bf16x8 Ahi_ = *(const bf16x8*)(&xh_hi[lr][(OFF) + 8 * lg]);                    \
    bf16x8 Alo_ = *(const bf16x8*)(&xh_lo[lr][(OFF) + 8 * lg]);                    \
    const unsigned short* wb_ = WBw + (size_t)(K) * KK_STRIDE;                     \
    bf16x8 BR0 = *(const bf16x8*)(wb_);                                            \
    bf16x8 BZ0 = *(const bf16x8*)(wb_ + 1024);                                     \
    bf16x8 BN0 = *(const bf16x8*)(wb_ + 2048);                                     \
    bf16x8 BR1 = *(const bf16x8*)(wb_ + 3072);                                     \
    bf16x8 BZ1 = *(const bf16x8*)(wb_ + 4096);                                     \
    bf16x8 BN1 = *(const bf16x8*)(wb_ + 5120);                                     \
    aR[0]   = MF(Ahi_, BR0, aR[0]);   aR[0]   = MF(Alo_, BR0, aR[0]);              \
    aZ[0]   = MF(Ahi_, BZ0, aZ[0]);   aZ[0]   = MF(Alo_, BZ0, aZ[0]);              \
    ACCN[0] = MF(Ahi_, BN0, ACCN[0]); ACCN[0] = MF(Alo_, BN0, ACCN[0]);            \
    aR[1]   = MF(Ahi_, BR1, aR[1]);   aR[1]   = MF(Alo_, BR1, aR[1]);              \
    aZ[1]   = MF(Ahi_, BZ1, aZ[1]);   aZ[1]   = MF(Alo_, BZ1, aZ[1]);              \
    ACCN[1] = MF(Ahi_, BN1, ACCN[1]); ACCN[1] = MF(Alo_, BN1, ACCN[1]); }

// 512 threads = 8 waves, 1 block/CU (grid 176 < 256; LDS 123KB). Wave w owns
// channels j = 16*w + 128*c2 + lr. 2 waves/SIMD -> 256-reg budget: arch VGPRs
// for working set, accum half (AGPR) for 30 loop-invariant weight fragments.
__global__ void __launch_bounds__(512)
__attribute__((amdgpu_waves_per_eu(2, 2)))
gru_mfma(const int* __restrict__ obs_t, const int* __restrict__ obs_l,
         const int* __restrict__ look_t, const int* __restrict__ look_l,
         const int* __restrict__ inv_t, const int* __restrict__ inv_l,
         const int* __restrict__ act_t, const int* __restrict__ act_l,
         const float* __restrict__ emb, const float* __restrict__ bih,
         const float* __restrict__ bhh, const unsigned short* __restrict__ WB,
         float* __restrict__ state, float* __restrict__ act_out) {
    const int bid = blockIdx.x;
    // XCD-aware mapping: bid%8 ~ XCD. XCD pair {0,1}->enc0, {2,3}->enc1,
    // {4,5}->enc2; act fills XCDs 6,7 plus the leftover slots everywhere.
    const int x = bid & 7, rr = bid >> 3;   // grid = 176 -> rr in 0..21
    int enc, tile, S;
    const int* toks;
    const int* lens;
    if (x < 6 && rr < 8) {
        enc = x >> 1; tile = (x & 1) * 8 + rr; S = SLEN;
        toks = (enc == 0) ? obs_t : (enc == 1) ? look_t : inv_t;
        lens = (enc == 0) ? obs_l : (enc == 1) ? look_l : inv_l;
    } else {
        enc = 3; S = SALEN;
        tile = (x >= 6) ? (rr * 2 + (x - 6)) : (44 + (rr - 8) * 6 + x);
        toks = act_t; lens = act_l;
    }
    const int tid = threadIdx.x;
    const int l   = tid & 63;
    const int w   = tid >> 6;     // 0..7
    const int lr  = l & 15;
    const int lg  = l >> 4;

    __shared__ __align__(16) unsigned short xh_hi[TB][PADW];
    __shared__ __align__(16) unsigned short xh_lo[TB][PADW];
    __shared__ __align__(16) unsigned short wlds[2][8][6][512];   // 96KB: kk5,6

    // init h region [128,384) to zero: 512 threads x 8 shorts
    {
        int m = tid >> 5, c = tid & 31;
#pragma unroll
        for (int q = 0; q < 8; ++q) {
            xh_hi[m][EDIM + 8 * c + q] = 0;
            xh_lo[m][EDIM + 8 * c + q] = 0;
        }
    }

    int maxlen = 1;
    for (int s = 0; s < TB; ++s) {
        int L = lens[tile * TB + s];
        if (L < 1) L = 1;
        if (L > maxlen) maxlen = L;
    }
    int lenm[4];
#pragma unroll
    for (int i = 0; i < 4; ++i) {
        int L = lens[tile * TB + 4 * lg + i];
        lenm[i] = (L < 1) ? 1 : L;
    }

    float bR[2], bZ[2], bIN[2], bHN[2];
#pragma unroll
    for (int c2 = 0; c2 < 2; ++c2) {
        int j = 16 * w + 128 * c2 + lr;
        bR[c2]  = bih[enc * G3 + j] + bhh[enc * G3 + j];
        bZ[c2]  = bih[enc * G3 + 256 + j] + bhh[enc * G3 + 256 + j];
        bIN[c2] = bih[enc * G3 + 512 + j];
        bHN[c2] = bhh[enc * G3 + 512 + j];
    }

    float hO[2][4];
#pragma unroll
    for (int c2 = 0; c2 < 2; ++c2)
#pragma unroll
        for (int i = 0; i < 4; ++i) hO[c2][i] = 0.f;

    // stage x_t: 512 threads, each 4 floats of one seq row
    auto stage = [&](int tt) {
        int m = tid >> 5, g = tid & 31;
        int tok = toks[(tile * TB + m) * S + tt];
        const float4 v = *(const float4*)(emb + (size_t)tok * EDIM + g * 4);
        float vv[4] = {v.x, v.y, v.z, v.w};
        bf16x4 H, Lo;
#pragma unroll
        for (int q = 0; q < 4; ++q) {
            unsigned short h16 = bf16_rne(vv[q]);
            H[q]  = (short)h16;
            Lo[q] = (short)bf16_rne(vv[q] - bf16_to_f32(h16));
        }
        *(bf16x4*)(&xh_hi[m][g * 4]) = H;
        *(bf16x4*)(&xh_lo[m][g * 4]) = Lo;
    };

    // this wave's fragment base (slot-indexed; slots (c2*3+gate)*1024)
    const unsigned short* WBw = WB + (size_t)enc * (12 * KK_STRIDE)
                                   + w * WV_STRIDE + l * 8;

    // ---- one-time preload: kk2,3,4,7,8 -> 30 AGPR-resident fragments ----
    DECLA(2) DECLA(3) DECLA(4) DECLA(7) DECLA(8)

    // ---- one-time preload: kk5,6 into LDS (wave-local slices) ----
#pragma unroll
    for (int kki = 0; kki < 2; ++kki)
#pragma unroll
        for (int s = 0; s < 6; ++s)
            *(bf16x8*)(&wlds[kki][w][s][l * 8]) =
                *(const bf16x8*)(WBw + (size_t)(5 + kki) * KK_STRIDE + s * 1024);

    stage(0);
    __syncthreads();

    for (int t = 0; t < maxlen; ++t) {
        f32x4 aR[2], aZ[2], aNX[2], aNH[2];
#pragma unroll
        for (int c2 = 0; c2 < 2; ++c2) {
            aR[c2]  = (f32x4){0.f, 0.f, 0.f, 0.f};
            aZ[c2]  = (f32x4){0.f, 0.f, 0.f, 0.f};
            aNX[c2] = (f32x4){0.f, 0.f, 0.f, 0.f};
            aNH[c2] = (f32x4){0.f, 0.f, 0.f, 0.f};
        }

        // Hazard-safe ordering (SSA-enforced):
        //  1) streamed intrinsics FIRST-touch every accumulator the asm reads
        //  2) asm-AGPR MFMAs (srcC always MFMA-written -> HW forwarding)
        //  3) intrinsic MFMAs LAST-touch every accumulator (compiler inserts
        //     the MFMA->VALU hazard waits before the gates)
        STREAMK(0,  0,          aNX)   // x-part
        STREAMK(9,  EDIM + 160, aNH)   // h-part
        STREAMK(10, EDIM + 192, aNH)
        STREAMK(11, EDIM + 224, aNH)

        AGPRK(2, 64,         aNX)      // x-part
        AGPRK(3, 96,         aNX)
        AGPRK(4, EDIM + 0,   aNH)      // h-part
        AGPRK(7, EDIM + 96,  aNH)
        AGPRK(8, EDIM + 128, aNH)

        STREAMK(1, 32, aNX)            // x-part (aNX intrinsic-last)

        // ---- LDS tier: kk 5,6 (h-part; aR/aZ/aNH intrinsic-last) ----
#pragma unroll
        for (int kki = 0; kki < 2; ++kki) {
            const int off = EDIM + 32 * (1 + kki);
            bf16x8 Ahi = *(const bf16x8*)(&xh_hi[lr][off + 8 * lg]);
            bf16x8 Alo = *(const bf16x8*)(&xh_lo[lr][off + 8 * lg]);
            bf16x8 BR0 = *(const bf16x8*)(&wlds[kki][w][0][l * 8]);
            bf16x8 BZ0 = *(const bf16x8*)(&wlds[kki][w][1][l * 8]);
            bf16x8 BN0 = *(const bf16x8*)(&wlds[kki][w][2][l * 8]);
            bf16x8 BR1 = *(const bf16x8*)(&wlds[kki][w][3][l * 8]);
            bf16x8 BZ1 = *(const bf16x8*)(&wlds[kki][w][4][l * 8]);
            bf16x8 BN1 = *(const bf16x8*)(&wlds[kki][w][5][l * 8]);
            aR[0]  = MF(Ahi, BR0, aR[0]);  aR[0]  = MF(Alo, BR0, aR[0]);
            aZ[0]  = MF(Ahi, BZ0, aZ[0]);  aZ[0]  = MF(Alo, BZ0, aZ[0]);
            aNH[0] = MF(Ahi, BN0, aNH[0]); aNH[0] = MF(Alo, BN0, aNH[0]);
            aR[1]  = MF(Ahi, BR1, aR[1]);  aR[1]  = MF(Alo, BR1, aR[1]);
            aZ[1]  = MF(Ahi, BZ1, aZ[1]);  aZ[1]  = MF(Alo, BZ1, aZ[1]);
            aNH[1] = MF(Ahi, BN1, aNH[1]); aNH[1] = MF(Alo, BN1, aNH[1]);
        }

        __syncthreads();   // all xh reads of this step done

        // gates + h update (biases added here); C row m = 4*lg + i, col = lr
#pragma unroll
        for (int c2 = 0; c2 < 2; ++c2) {
            int j = 16 * w + 128 * c2 + lr;
#pragma unroll
            for (int i = 0; i < 4; ++i) {
                int m = 4 * lg + i;
                float r = 1.f / (1.f + expf(-(aR[c2][i] + bR[c2])));
                float z = 1.f / (1.f + expf(-(aZ[c2][i] + bZ[c2])));
                float n = tanhf(aNX[c2][i] + bIN[c2] + r * (aNH[c2][i] + bHN[c2]));
                float hv = (1.f - z) * n + z * hO[c2][i];
                hv = (t < lenm[i]) ? hv : hO[c2][i];
                hO[c2][i] = hv;
                unsigned short h16 = bf16_rne(hv);
                xh_hi[m][EDIM + j] = h16;
                xh_lo[m][EDIM + j] = bf16_rne(hv - bf16_to_f32(h16));
            }
        }
        if (t + 1 < maxlen) stage(t + 1);
        __syncthreads();
    }

    // outputs: lane owns (m = 4*lg+i, channels j(c2))
#pragma unroll
    for (int c2 = 0; c2 < 2; ++c2) {
        int j = 16 * w + 128 * c2 + lr;
#pragma unroll
        for (int i = 0; i < 4; ++i) {
            int sg = tile * TB + 4 * lg + i;
            if (enc < 3) state[sg * G3 + enc * HDIM + j] = hO[c2][i];
            else         act_out[sg * HDIM + j] = hO[c2][i];
        }
    }
}

__global__ void __launch_bounds__(256)
mlp_kernel(const float* __restrict__ state, const float* __restrict__ act_out,
           const float* __restrict__ hWT, const float* __restrict__ hb,
           const float* __restrict__ sW, const float* __restrict__ sb,
           float* __restrict__ q) {
    int b = blockIdx.x;
    int j = threadIdx.x;
    __shared__ float st[G3];
    __shared__ float ab[ANUM][HDIM];
#pragma unroll
    for (int i = 0; i < 3; ++i) st[i * 256 + j] = state[b * G3 + i * 256 + j];
#pragma unroll
    for (int i = 0; i < ANUM; ++i) ab[i][j] = act_out[(b * ANUM + i) * HDIM + j];
    __syncthreads();

    float accS = 0.f;
#pragma unroll 4
    for (int k = 0; k < G3; ++k) accS += st[k] * hWT[k * HDIM + j];

    float accA[ANUM];
#pragma unroll
    for (int i = 0; i < ANUM; ++i) accA[i] = 0.f;
    for (int k = 0; k < HDIM; ++k) {
        float w = hWT[(G3 + k) * HDIM + j];
#pragma unroll
        for (int i = 0; i < ANUM; ++i) accA[i] += ab[i][k] * w;
    }

    float base = hb[j] + accS;
    float p[ANUM];
#pragma unroll
    for (int i = 0; i < ANUM; ++i) {
        float zz = base + accA[i];
        zz = zz > 0.f ? zz : 0.f;
        p[i] = zz * sW[j];
    }

    __shared__ float wsum[ANUM][4];
#pragma unroll
    for (int i = 0; i < ANUM; ++i) {
        float v = p[i];
        for (int off = 32; off >= 1; off >>= 1) v += __shfl_down(v, off, 64);
        if ((j & 63) == 0) wsum[i][j >> 6] = v;
    }
    __syncthreads();
    if (j < ANUM) q[b * ANUM + j] = wsum[j][0] + wsum[j][1] + wsum[j][2] + wsum[j][3] + sb[0];
}

extern "C" void kernel_launch(void* const* d_in, const int* in_sizes, int n_in,
                              void* d_out, int out_size, void* d_ws, size_t ws_size,
                              hipStream_t stream) {
    const int* obs_t  = (const int*)d_in[0];
    const int* obs_l  = (const int*)d_in[1];
    const int* look_t = (const int*)d_in[2];
    const int* look_l = (const int*)d_in[3];
    const int* inv_t  = (const int*)d_in[4];
    const int* inv_l  = (const int*)d_in[5];
    const int* act_t  = (const int*)d_in[6];
    const int* act_l  = (const int*)d_in[7];
    const float* emb  = (const float*)d_in[8];
    const float* Wih  = (const float*)d_in[9];
    const float* Whh  = (const float*)d_in[10];
    const float* bih  = (const float*)d_in[11];
    const float* bhh  = (const float*)d_in[12];
    const float* hW   = (const float*)d_in[13];
    const float* hb   = (const float*)d_in[14];
    const float* sW   = (const float*)d_in[15];
    const float* sb   = (const float*)d_in[16];

    float* ws    = (float*)d_ws;
    unsigned short* WB = (unsigned short*)d_ws;
    float* hWT   = ws + OFF_HWT;
    float* state = ws + OFF_STATE;
    float* act_o = ws + OFF_ACT;

    prep_frag<<<(WB_SHORTS / 2 + 255) / 256, 256, 0, stream>>>(Wih, Whh, WB);
    prep_hwt<<<(HWT_SIZE + 255) / 256, 256, 0, stream>>>(hW, hWT);
    gru_mfma<<<176, 512, 0, stream>>>(obs_t, obs_l, look_t, look_l, inv_t, inv_l,
                                      act_t, act_l, emb, bih, bhh, WB,
                                      state, act_o);
    mlp_kernel<<<256, 256, 0, stream>>>(state, act_o, hWT, hb, sW, sb, (float*)d_out);
}

// Round 16
// 1342.017 us; speedup vs baseline: 1.9625x; 1.9625x over previous
//
#include <hip/hip_runtime.h>
#include <math.h>

#define VSZ 32000
#define EDIM 128
#define HDIM 256
#define BSZ 256
#define SLEN 256
#define ANUM 8
#define SALEN 32
#define G3 768
#define TB 16            // sequences per block (one M-tile)
#define PADW 392         // xh row length in shorts (384 + 8 pad)

// WB: split-bf16 weight fragments: [enc4][kk12][wv8][slot6][hi/lo 2][512 shorts]
// slot = c2*3 + gate. Recurrence uses hi-only weights; A-side (x,h) split hi+lo.
// Residency: kk5,6 fully in LDS (96KB) + kk4's R,Z in LDS (32KB); rest streamed
// from L2 (448 KB/step). Register/AGPR residency abandoned for good: r11-r13
// (launch_bounds / waves_per_eu) and r15 (inline-asm "a" constraint) all spill
// - the allocator will not hold loop-invariant MFMA operands.
#define WB_SHORTS (4 * 12 * 8 * 6 * 2 * 512)    // 2,359,296 shorts = 4.72 MB
#define KK_STRIDE (8 * 6 * 2 * 512)             // 49152 shorts per kk
#define WV_STRIDE (6 * 2 * 512)                 // 6144 shorts per wv
#define OFF_HWT   (WB_SHORTS / 2)               // float offset
#define HWT_SIZE  (1024 * HDIM)
#define OFF_STATE (OFF_HWT + HWT_SIZE)
#define OFF_ACT   (OFF_STATE + BSZ * G3)

typedef __attribute__((ext_vector_type(8))) short bf16x8;
typedef __attribute__((ext_vector_type(4))) short bf16x4;
typedef __attribute__((ext_vector_type(4))) float f32x4;

__device__ __forceinline__ unsigned short bf16_rne(float f) {
    unsigned int u = __builtin_bit_cast(unsigned int, f);
    unsigned int r = (u + 0x7FFFu + ((u >> 16) & 1u)) >> 16;
    return (unsigned short)r;
}
__device__ __forceinline__ float bf16_to_f32(unsigned short h) {
    unsigned int u = ((unsigned int)h) << 16;
    return __builtin_bit_cast(float, u);
}

// B-fragment: lane l elem q -> B[k = 32*kk + 8*(l>>4) + q][n], n = 256*g3 + 16*(wv+8*cc2) + (l&15)
__global__ void prep_frag(const float* __restrict__ Wih, const float* __restrict__ Whh,
                          unsigned short* __restrict__ WB) {
    int idx = blockIdx.x * 256 + threadIdx.x;      // < 1,179,648 (hi elements)
    int q = idx & 7;
    int l = (idx >> 3) & 63;
    int rest = idx >> 9;
    int slot = rest % 6; rest /= 6;                // slot = cc2*3 + g3
    int wv = rest & 7;   rest >>= 3;
    int kk = rest % 12;
    int enc = rest / 12;
    int cc2 = slot / 3, g3 = slot % 3;
    int row = 256 * g3 + 16 * (wv + 8 * cc2) + (l & 15);
    int kloc = 8 * (l >> 4) + q;
    float v;
    if (kk < 4) v = Wih[(enc * G3 + row) * EDIM + 32 * kk + kloc];
    else        v = Whh[(enc * G3 + row) * HDIM + 32 * (kk - 4) + kloc];
    unsigned short hi = bf16_rne(v);
    unsigned short lo = bf16_rne(v - bf16_to_f32(hi));
    size_t base = ((((size_t)(enc * 12 + kk) * 8 + wv) * 6 + slot) * 2) * 512 + l * 8 + q;
    WB[base] = hi;
    WB[base + 512] = lo;
}

__global__ void prep_hwt(const float* __restrict__ hW, float* __restrict__ hWT) {
    int idx = blockIdx.x * 256 + threadIdx.x;
    if (idx >= HWT_SIZE) return;
    int k = idx >> 8;
    int j = idx & 255;
    hWT[idx] = hW[j * 1024 + k];
}

#define MF(A, B, C) __builtin_amdgcn_mfma_f32_16x16x32_bf16(A, B, C, 0, 0, 0)

// 1024 threads = 16 waves. Wave w owns ONE channel-tile: channels
// j = 16*(w&7) + 128*(w>>3) + lr. 4 waves/SIMD (VGPR ~64, no residency attempt).
// Gate weights pure bf16 (hi); A-side (x,h) split hi+lo.
__global__ void __launch_bounds__(1024, 1)
gru_mfma(const int* __restrict__ obs_t, const int* __restrict__ obs_l,
         const int* __restrict__ look_t, const int* __restrict__ look_l,
         const int* __restrict__ inv_t, const int* __restrict__ inv_l,
         const int* __restrict__ act_t, const int* __restrict__ act_l,
         const float* __restrict__ emb, const float* __restrict__ bih,
         const float* __restrict__ bhh, const unsigned short* __restrict__ WB,
         float* __restrict__ state, float* __restrict__ act_out) {
    const int bid = blockIdx.x;
    // XCD-aware mapping: bid%8 ~ XCD. XCD pair {0,1}->enc0, {2,3}->enc1,
    // {4,5}->enc2; act fills XCDs 6,7 plus the leftover slots everywhere.
    const int x = bid & 7, rr = bid >> 3;   // grid = 176 -> rr in 0..21
    int enc, tile, S;
    const int* toks;
    const int* lens;
    if (x < 6 && rr < 8) {
        enc = x >> 1; tile = (x & 1) * 8 + rr; S = SLEN;
        toks = (enc == 0) ? obs_t : (enc == 1) ? look_t : inv_t;
        lens = (enc == 0) ? obs_l : (enc == 1) ? look_l : inv_l;
    } else {
        enc = 3; S = SALEN;
        tile = (x >= 6) ? (rr * 2 + (x - 6)) : (44 + (rr - 8) * 6 + x);
        toks = act_t; lens = act_l;
    }
    const int tid = threadIdx.x;
    const int l   = tid & 63;
    const int w   = tid >> 6;     // 0..15
    const int wvb = w & 7;        // WB wv index
    const int c2  = w >> 3;       // slot group
    const int lr  = l & 15;
    const int lg  = l >> 4;
    const int j   = 16 * wvb + 128 * c2 + lr;   // owned channel

    __shared__ __align__(16) unsigned short xh_hi[TB][PADW];
    __shared__ __align__(16) unsigned short xh_lo[TB][PADW];
    __shared__ __align__(16) unsigned short wlds[2][16][3][512];   // 96KB: kk5,6
    __shared__ __align__(16) unsigned short wlds2[16][2][512];     // 32KB: kk4 R,Z

    // init h region [128,384) to zero (first 512 threads)
    if (tid < 512) {
        int m = tid >> 5, c = tid & 31;
#pragma unroll
        for (int q = 0; q < 8; ++q) {
            xh_hi[m][EDIM + 8 * c + q] = 0;
            xh_lo[m][EDIM + 8 * c + q] = 0;
        }
    }

    int maxlen = 1;
    for (int s = 0; s < TB; ++s) {
        int L = lens[tile * TB + s];
        if (L < 1) L = 1;
        if (L > maxlen) maxlen = L;
    }
    int lenm[4];
#pragma unroll
    for (int i = 0; i < 4; ++i) {
        int L = lens[tile * TB + 4 * lg + i];
        lenm[i] = (L < 1) ? 1 : L;
    }

    const float bR  = bih[enc * G3 + j] + bhh[enc * G3 + j];
    const float bZ  = bih[enc * G3 + 256 + j] + bhh[enc * G3 + 256 + j];
    const float bIN = bih[enc * G3 + 512 + j];
    const float bHN = bhh[enc * G3 + 512 + j];

    float hO[4];
#pragma unroll
    for (int i = 0; i < 4; ++i) hO[i] = 0.f;

    // stage x_t: first 512 threads, each 4 floats of one seq row
    auto stage = [&](int tt) {
        if (tid < 512) {
            int m = tid >> 5, g = tid & 31;
            int tok = toks[(tile * TB + m) * S + tt];
            const float4 v = *(const float4*)(emb + (size_t)tok * EDIM + g * 4);
            float vv[4] = {v.x, v.y, v.z, v.w};
            bf16x4 H, Lo;
#pragma unroll
            for (int q = 0; q < 4; ++q) {
                unsigned short h16 = bf16_rne(vv[q]);
                H[q]  = (short)h16;
                Lo[q] = (short)bf16_rne(vv[q] - bf16_to_f32(h16));
            }
            *(bf16x4*)(&xh_hi[m][g * 4]) = H;
            *(bf16x4*)(&xh_lo[m][g * 4]) = Lo;
        }
    };

    // this wave's fragment base: its wv slice, its c2 slot group
    const unsigned short* WBw = WB + (size_t)enc * (12 * KK_STRIDE)
                                   + wvb * WV_STRIDE + (c2 * 3) * 1024 + l * 8;

    // ---- one-time preload: kk5,6 into LDS (wave-local slices) ----
#pragma unroll
    for (int kki = 0; kki < 2; ++kki)
#pragma unroll
        for (int g = 0; g < 3; ++g)
            *(bf16x8*)(&wlds[kki][w][g][l * 8]) =
                *(const bf16x8*)(WBw + (size_t)(5 + kki) * KK_STRIDE + g * 1024);

    // ---- one-time preload: kk4 R,Z into LDS ----
    *(bf16x8*)(&wlds2[w][0][l * 8]) = *(const bf16x8*)(WBw + (size_t)4 * KK_STRIDE);
    *(bf16x8*)(&wlds2[w][1][l * 8]) = *(const bf16x8*)(WBw + (size_t)4 * KK_STRIDE + 1024);

    stage(0);
    __syncthreads();

    for (int t = 0; t < maxlen; ++t) {
        f32x4 aR  = (f32x4){bR, bR, bR, bR};
        f32x4 aZ  = (f32x4){bZ, bZ, bZ, bZ};
        f32x4 aNX = (f32x4){bIN, bIN, bIN, bIN};
        f32x4 aNH = (f32x4){bHN, bHN, bHN, bHN};

        // ---- streamed tier: kk 0..3 (x-part, n -> aNX) ----
#pragma unroll 2
        for (int kk = 0; kk < 4; ++kk) {
            const int off = 32 * kk;
            bf16x8 Ahi = *(const bf16x8*)(&xh_hi[lr][off + 8 * lg]);
            bf16x8 Alo = *(const bf16x8*)(&xh_lo[lr][off + 8 * lg]);
            const unsigned short* wb = WBw + (size_t)kk * KK_STRIDE;
            bf16x8 BhR = *(const bf16x8*)(wb);
            bf16x8 BhZ = *(const bf16x8*)(wb + 1024);
            bf16x8 BhN = *(const bf16x8*)(wb + 2048);
            aR  = MF(Ahi, BhR, aR);  aR  = MF(Alo, BhR, aR);
            aZ  = MF(Ahi, BhZ, aZ);  aZ  = MF(Alo, BhZ, aZ);
            aNX = MF(Ahi, BhN, aNX); aNX = MF(Alo, BhN, aNX);
        }

        // ---- kk 4 (h-part): R,Z from LDS, N streamed ----
        {
            const int off = EDIM;
            bf16x8 Ahi = *(const bf16x8*)(&xh_hi[lr][off + 8 * lg]);
            bf16x8 Alo = *(const bf16x8*)(&xh_lo[lr][off + 8 * lg]);
            bf16x8 BhR = *(const bf16x8*)(&wlds2[w][0][l * 8]);
            bf16x8 BhZ = *(const bf16x8*)(&wlds2[w][1][l * 8]);
            bf16x8 BhN = *(const bf16x8*)(WBw + (size_t)4 * KK_STRIDE + 2048);
            aR  = MF(Ahi, BhR, aR);  aR  = MF(Alo, BhR, aR);
            aZ  = MF(Ahi, BhZ, aZ);  aZ  = MF(Alo, BhZ, aZ);
            aNH = MF(Ahi, BhN, aNH); aNH = MF(Alo, BhN, aNH);
        }

        // ---- streamed tier: kk 7..11 (h-part, n -> aNH) ----
#pragma unroll 2
        for (int kk = 7; kk < 12; ++kk) {
            const int off = EDIM + 32 * (kk - 4);
            bf16x8 Ahi = *(const bf16x8*)(&xh_hi[lr][off + 8 * lg]);
            bf16x8 Alo = *(const bf16x8*)(&xh_lo[lr][off + 8 * lg]);
            const unsigned short* wb = WBw + (size_t)kk * KK_STRIDE;
            bf16x8 BhR = *(const bf16x8*)(wb);
            bf16x8 BhZ = *(const bf16x8*)(wb + 1024);
            bf16x8 BhN = *(const bf16x8*)(wb + 2048);
            aR  = MF(Ahi, BhR, aR);  aR  = MF(Alo, BhR, aR);
            aZ  = MF(Ahi, BhZ, aZ);  aZ  = MF(Alo, BhZ, aZ);
            aNH = MF(Ahi, BhN, aNH); aNH = MF(Alo, BhN, aNH);
        }

        // ---- LDS tier: kk 5,6 (h-part, n -> aNH) ----
#pragma unroll
        for (int kki = 0; kki < 2; ++kki) {
            const int off = EDIM + 32 * (1 + kki);
            bf16x8 Ahi = *(const bf16x8*)(&xh_hi[lr][off + 8 * lg]);
            bf16x8 Alo = *(const bf16x8*)(&xh_lo[lr][off + 8 * lg]);
            bf16x8 BhR = *(const bf16x8*)(&wlds[kki][w][0][l * 8]);
            bf16x8 BhZ = *(const bf16x8*)(&wlds[kki][w][1][l * 8]);
            bf16x8 BhN = *(const bf16x8*)(&wlds[kki][w][2][l * 8]);
            aR  = MF(Ahi, BhR, aR);  aR  = MF(Alo, BhR, aR);
            aZ  = MF(Ahi, BhZ, aZ);  aZ  = MF(Alo, BhZ, aZ);
            aNH = MF(Ahi, BhN, aNH); aNH = MF(Alo, BhN, aNH);
        }

        __syncthreads();   // all xh reads of this step done

        // gates + h update; C layout: row m = 4*lg + i, col = lr
#pragma unroll
        for (int i = 0; i < 4; ++i) {
            int m = 4 * lg + i;
            float r = 1.f / (1.f + expf(-aR[i]));
            float z = 1.f / (1.f + expf(-aZ[i]));
            float n = tanhf(aNX[i] + r * aNH[i]);
            float hv = (1.f - z) * n + z * hO[i];
            hv = (t < lenm[i]) ? hv : hO[i];
            hO[i] = hv;
            unsigned short h16 = bf16_rne(hv);
            xh_hi[m][EDIM + j] = h16;
            xh_lo[m][EDIM + j] = bf16_rne(hv - bf16_to_f32(h16));
        }
        if (t + 1 < maxlen) stage(t + 1);
        __syncthreads();
    }

    // outputs: lane owns (m = 4*lg+i, channel j)
#pragma unroll
    for (int i = 0; i < 4; ++i) {
        int sg = tile * TB + 4 * lg + i;
        if (enc < 3) state[sg * G3 + enc * HDIM + j] = hO[i];
        else         act_out[sg * HDIM + j] = hO[i];
    }
}

__global__ void __launch_bounds__(256)
mlp_kernel(const float* __restrict__ state, const float* __restrict__ act_out,
           const float* __restrict__ hWT, const float* __restrict__ hb,
           const float* __restrict__ sW, const float* __restrict__ sb,
           float* __restrict__ q) {
    int b = blockIdx.x;
    int j = threadIdx.x;
    __shared__ float st[G3];
    __shared__ float ab[ANUM][HDIM];
#pragma unroll
    for (int i = 0; i < 3; ++i) st[i * 256 + j] = state[b * G3 + i * 256 + j];
#pragma unroll
    for (int i = 0; i < ANUM; ++i) ab[i][j] = act_out[(b * ANUM + i) * HDIM + j];
    __syncthreads();

    float accS = 0.f;
#pragma unroll 4
    for (int k = 0; k < G3; ++k) accS += st[k] * hWT[k * HDIM + j];

    float accA[ANUM];
#pragma unroll
    for (int i = 0; i < ANUM; ++i) accA[i] = 0.f;
    for (int k = 0; k < HDIM; ++k) {
        float w = hWT[(G3 + k) * HDIM + j];
#pragma unroll
        for (int i = 0; i < ANUM; ++i) accA[i] += ab[i][k] * w;
    }

    float base = hb[j] + accS;
    float p[ANUM];
#pragma unroll
    for (int i = 0; i < ANUM; ++i) {
        float zz = base + accA[i];
        zz = zz > 0.f ? zz : 0.f;
        p[i] = zz * sW[j];
    }

    __shared__ float wsum[ANUM][4];
#pragma unroll
    for (int i = 0; i < ANUM; ++i) {
        float v = p[i];
        for (int off = 32; off >= 1; off >>= 1) v += __shfl_down(v, off, 64);
        if ((j & 63) == 0) wsum[i][j >> 6] = v;
    }
    __syncthreads();
    if (j < ANUM) q[b * ANUM + j] = wsum[j][0] + wsum[j][1] + wsum[j][2] + wsum[j][3] + sb[0];
}

extern "C" void kernel_launch(void* const* d_in, const int* in_sizes, int n_in,
                              void* d_out, int out_size, void* d_ws, size_t ws_size,
                              hipStream_t stream) {
    const int* obs_t  = (const int*)d_in[0];
    const int* obs_l  = (const int*)d_in[1];
    const int* look_t = (const int*)d_in[2];
    const int* look_l = (const int*)d_in[3];
    const int* inv_t  = (const int*)d_in[4];
    const int* inv_l  = (const int*)d_in[5];
    const int* act_t  = (const int*)d_in[6];
    const int* act_l  = (const int*)d_in[7];
    const float* emb  = (const float*)d_in[8];
    const float* Wih  = (const float*)d_in[9];
    const float* Whh  = (const float*)d_in[10];
    const float* bih  = (const float*)d_in[11];
    const float* bhh  = (const float*)d_in[12];
    const float* hW   = (const float*)d_in[13];
    const float* hb   = (const float*)d_in[14];
    const float* sW   = (const float*)d_in[15];
    const float* sb   = (const float*)d_in[16];

    float* ws    = (float*)d_ws;
    unsigned short* WB = (unsigned short*)d_ws;
    float* hWT   = ws + OFF_HWT;
    float* state = ws + OFF_STATE;
    float* act_o = ws + OFF_ACT;

    prep_frag<<<(WB_SHORTS / 2 + 255) / 256, 256, 0, stream>>>(Wih, Whh, WB);
    prep_hwt<<<(HWT_SIZE + 255) / 256, 256, 0, stream>>>(hW, hWT);
    gru_mfma<<<176, 1024, 0, stream>>>(obs_t, obs_l, look_t, look_l, inv_t, inv_l,
                                       act_t, act_l, emb, bih, bhh, WB,
                                       state, act_o);
    mlp_kernel<<<256, 256, 0, stream>>>(state, act_o, hWT, hb, sW, sb, (float*)d_out);
}